// Round 14
// baseline (678.303 us; speedup 1.0000x reference)
//
#include <hip/hip_runtime.h>
#include <stdint.h>

typedef unsigned short u16;
typedef __bf16 bf16x8 __attribute__((ext_vector_type(8)));
typedef float f32x4 __attribute__((ext_vector_type(4)));

typedef const __attribute__((address_space(1))) uint32_t* gu32p;
typedef __attribute__((address_space(3))) uint32_t* lu32p;
#define GLOAD_LDS16(g, l) \
  __builtin_amdgcn_global_load_lds((gu32p)(const void*)(g), (lu32p)(void*)(l), 16, 0, 0)

static __device__ __forceinline__ u16 f2bf(float f) {
  uint32_t u = __builtin_bit_cast(uint32_t, f);
  return (u16)((u + 0x7FFFu + ((u >> 16) & 1u)) >> 16);
}
static __device__ __forceinline__ float bf2f(u16 h) {
  uint32_t u = ((uint32_t)h) << 16;
  return __builtin_bit_cast(float, u);
}

// ---------------- fused fp32 -> bf16 conversion (all 6 regions, 1 launch) ----------------
__global__ __launch_bounds__(256) void k_conv_all(
    const float* __restrict__ s0, u16* __restrict__ d0,   // input   8M elems, blocks [0,8192)
    const float* __restrict__ s1, u16* __restrict__ d1,   // context 1M, [8192,9216)
    const float* __restrict__ s2, u16* __restrict__ d2,   // Wqi     3M, [9216,12288)
    const float* __restrict__ s3, u16* __restrict__ d3,   // Wqc     3M, [12288,15360)
    const float* __restrict__ s4, u16* __restrict__ d4,   // Woi     1M, [15360,16384)
    const float* __restrict__ s5, u16* __restrict__ d5) { // Woc     1M, [16384,17408)
  int b = blockIdx.x;
  const float* src; u16* dst; long off;
  if (b < 8192)       { src = s0; dst = d0; off = (long)b * 1024; }
  else if (b < 9216)  { src = s1; dst = d1; off = (long)(b - 8192) * 1024; }
  else if (b < 12288) { src = s2; dst = d2; off = (long)(b - 9216) * 1024; }
  else if (b < 15360) { src = s3; dst = d3; off = (long)(b - 12288) * 1024; }
  else if (b < 16384) { src = s4; dst = d4; off = (long)(b - 15360) * 1024; }
  else                { src = s5; dst = d5; off = (long)(b - 16384) * 1024; }
  long i = off + threadIdx.x * 4;
  const float4 v = *(const float4*)&src[i];
  ushort4 o;
  o.x = f2bf(v.x); o.y = f2bf(v.y); o.z = f2bf(v.z); o.w = f2bf(v.w);
  *(ushort4*)&dst[i] = o;
}

// ---------------- 128x128 MFMA tile core, BK=64, swizzled, 2-dbuf (r12 best) ----------------
// 256 threads = 4 waves (2M x 2N); per-wave 64x64 = acc[4][4]. LDS 64 KiB -> 2 blocks/CU.
// Swizzle: LDS 16B-slot L of row r holds global slot L^(r&7) (involution; 0 conflicts).
__device__ __forceinline__ void gemm_bk64(const u16* __restrict__ A, const u16* __restrict__ Bt,
                                          int lda, int ldb, long row0, long col0,
                                          int kbeg, int kend, u16* smem, f32x4 acc[4][4]) {
  const int tid = threadIdx.x;
  const int l = tid & 63;
  const int w = tid >> 6;
  const int wm = w >> 1, wn = w & 1;
  const int lr = l & 15, kg = l >> 4;
  const int swz = (lr & 7) * 8;                    // read-side XOR (elems)
  const int r_l = tid >> 3;                        // 0..31
  const int ssrc = ((tid & 7) ^ (r_l & 7)) * 8;    // pre-swizzled source col (elems)
  const u16* gA = &A[(row0 + r_l) * (long)lda + ssrc];
  const u16* gB = &Bt[(col0 + r_l) * (long)ldb + ssrc];
  u16* const ldsA = smem + w * 512;                // wave-uniform bases (elems)
  u16* const ldsB = smem + 8192 + w * 512;
  const int NT = (kend - kbeg) >> 6;

  { // prologue: tile 0 -> dbuf 0
#pragma unroll
    for (int c = 0; c < 4; ++c) {
      GLOAD_LDS16(gA + (c * 32) * (long)lda + kbeg, ldsA + c * 2048);
      GLOAD_LDS16(gB + (c * 32) * (long)ldb + kbeg, ldsB + c * 2048);
    }
  }
  asm volatile("s_waitcnt vmcnt(0)" ::: "memory");
  __builtin_amdgcn_s_barrier();
  __builtin_amdgcn_sched_barrier(0);

  for (int t = 0; t < NT; ++t) {
    const int d = (t & 1) << 14;                   // dbuf offset (elems)
    const int dn = ((t + 1) & 1) << 14;
    const bool pf = (t + 1 < NT);
    const long k1 = kbeg + (long)(t + 1) * 64;
    bf16x8 af[4], bv[4];
    // ---- phase 0: stage A(t+1); compute k-step s=0 ----
    if (pf) {
#pragma unroll
      for (int c = 0; c < 4; ++c)
        GLOAD_LDS16(gA + (c * 32) * (long)lda + k1, ldsA + dn + c * 2048);
    }
#pragma unroll
    for (int i = 0; i < 4; ++i) {
      af[i] = *(const bf16x8*)&smem[d + (wm * 64 + i * 16 + lr) * 64 + (kg * 8 ^ swz)];
      bv[i] = *(const bf16x8*)&smem[d + 8192 + (wn * 64 + i * 16 + lr) * 64 + (kg * 8 ^ swz)];
    }
    __builtin_amdgcn_s_setprio(1);
#pragma unroll
    for (int mf = 0; mf < 4; ++mf)
#pragma unroll
      for (int nf = 0; nf < 4; ++nf)
        acc[mf][nf] = __builtin_amdgcn_mfma_f32_16x16x32_bf16(af[mf], bv[nf], acc[mf][nf], 0, 0, 0);
    __builtin_amdgcn_s_setprio(0);
    // ---- phase 1: stage B(t+1); compute k-step s=1 ----
    if (pf) {
#pragma unroll
      for (int c = 0; c < 4; ++c)
        GLOAD_LDS16(gB + (c * 32) * (long)ldb + k1, ldsB + dn + c * 2048);
    }
#pragma unroll
    for (int i = 0; i < 4; ++i) {
      af[i] = *(const bf16x8*)&smem[d + (wm * 64 + i * 16 + lr) * 64 + ((32 + kg * 8) ^ swz)];
      bv[i] = *(const bf16x8*)&smem[d + 8192 + (wn * 64 + i * 16 + lr) * 64 + ((32 + kg * 8) ^ swz)];
    }
    __builtin_amdgcn_s_setprio(1);
#pragma unroll
    for (int mf = 0; mf < 4; ++mf)
#pragma unroll
      for (int nf = 0; nf < 4; ++nf)
        acc[mf][nf] = __builtin_amdgcn_mfma_f32_16x16x32_bf16(af[mf], bv[nf], acc[mf][nf], 0, 0, 0);
    __builtin_amdgcn_s_setprio(0);
    asm volatile("s_waitcnt vmcnt(0)" ::: "memory");  // t+1 stage landed; mostly shadowed
    __builtin_amdgcn_s_barrier();
    __builtin_amdgcn_sched_barrier(0);
  }
}

// -------- 128x128 core, BK=64, swizzled, SINGLE buffer (32 KiB -> 5 blocks/CU) --------
// m97 mechanism at BK=64: no explicit prefetch; the vmcnt drain at each barrier is
// hidden by 5-way inter-block TLP (m114). Same swizzle/read layout as gemm_bk64.
__device__ __forceinline__ void gemm_sb64(const u16* __restrict__ A, const u16* __restrict__ Bt,
                                          int lda, int ldb, long row0, long col0,
                                          int kbeg, int kend, u16* smem, f32x4 acc[4][4]) {
  const int tid = threadIdx.x;
  const int l = tid & 63;
  const int w = tid >> 6;
  const int wm = w >> 1, wn = w & 1;
  const int lr = l & 15, kg = l >> 4;
  const int swz = (lr & 7) * 8;
  const int r_l = tid >> 3;
  const int ssrc = ((tid & 7) ^ (r_l & 7)) * 8;
  const u16* gA = &A[(row0 + r_l) * (long)lda + ssrc];
  const u16* gB = &Bt[(col0 + r_l) * (long)ldb + ssrc];
  u16* const ldsA = smem + w * 512;
  u16* const ldsB = smem + 8192 + w * 512;

  for (int k0 = kbeg; k0 < kend; k0 += 64) {
#pragma unroll
    for (int c = 0; c < 4; ++c) {
      GLOAD_LDS16(gA + (c * 32) * (long)lda + k0, ldsA + c * 2048);
      GLOAD_LDS16(gB + (c * 32) * (long)ldb + k0, ldsB + c * 2048);
    }
    __syncthreads();                               // drains vmcnt; hidden by 5-way TLP
    bf16x8 af[4], bv[4];
#pragma unroll
    for (int s = 0; s < 2; ++s) {
      const int ko = s * 32;
#pragma unroll
      for (int i = 0; i < 4; ++i) {
        af[i] = *(const bf16x8*)&smem[(wm * 64 + i * 16 + lr) * 64 + ((ko + kg * 8) ^ swz)];
        bv[i] = *(const bf16x8*)&smem[8192 + (wn * 64 + i * 16 + lr) * 64 + ((ko + kg * 8) ^ swz)];
      }
#pragma unroll
      for (int mf = 0; mf < 4; ++mf)
#pragma unroll
        for (int nf = 0; nf < 4; ++nf)
          acc[mf][nf] = __builtin_amdgcn_mfma_f32_16x16x32_bf16(af[mf], bv[nf], acc[mf][nf], 0, 0, 0);
    }
    __syncthreads();
  }
}

#define EPI_VARS                                   \
  const int l = threadIdx.x & 63;                  \
  const int w = threadIdx.x >> 6;                  \
  const int wm = w >> 1, wn = w & 1;               \
  const int mrow = (l >> 4) * 4, ncol = l & 15;

// ---------------- QKV projection (input + context merged) ----------------
__global__ __launch_bounds__(256, 2) void k_gemm_qkv(
    const u16* __restrict__ XIN, const u16* __restrict__ XCTX,
    const u16* __restrict__ WQI, const u16* __restrict__ WQC,
    const float* __restrict__ bqi, const float* __restrict__ bqc,
    u16* __restrict__ qb, u16* __restrict__ kb, u16* __restrict__ vt) {
  __shared__ u16 smem[32768];
  f32x4 acc[4][4] = {};
  const bool isCtx = blockIdx.x >= 64;
  const u16* X = isCtx ? XCTX : XIN;
  const u16* W = isCtx ? WQC : WQI;
  const float* bias = isCtx ? bqc : bqi;
  const int seg_start = isCtx ? 0 : 512;
  long row0 = (long)(isCtx ? blockIdx.x - 64 : blockIdx.x) * 128;
  long col0 = (long)blockIdx.y * 128;
  gemm_bk64(X, W, 1024, 1024, row0, col0, 0, 1024, smem, acc);
  EPI_VARS
#pragma unroll
  for (int mf = 0; mf < 4; ++mf)
#pragma unroll
    for (int nf = 0; nf < 4; ++nf)
#pragma unroll
      for (int r = 0; r < 4; ++r) {
        int m = (int)row0 + wm * 64 + mf * 16 + mrow + r;
        int n = (int)col0 + wn * 64 + nf * 16 + ncol;
        float v = acc[mf][nf][r] + bias[n];
        int b, s;
        if (isCtx) { b = m >> 9; s = m & 511; } else { b = m >> 12; s = m & 4095; }
        long grow = (long)b * 4608 + seg_start + s;
        if (n < 1024)      qb[grow * 1024 + n] = f2bf(v);
        else if (n < 2048) kb[grow * 1024 + (n - 1024)] = f2bf(v);
        else               vt[((long)b * 1024 + (n - 2048)) * 4608 + seg_start + s] = f2bf(v);
      }
}

// ---------------- RMSNorm + RoPE (in-place on q_buf / k_buf), vectorized ----------------
__global__ __launch_bounds__(256) void k_normrope(u16* __restrict__ qb, u16* __restrict__ kb,
                                                  const float* __restrict__ qsi, const float* __restrict__ ksi,
                                                  const float* __restrict__ qsc, const float* __restrict__ ksc) {
  __shared__ float sm[4];
  const int row = blockIdx.x;    // 0..9215  (b*4608 + n)
  const int which = blockIdx.y;  // 0 = q, 1 = k
  const int n = row % 4608;
  u16* buf = which ? kb : qb;
  const float* scale = which ? (n < 512 ? ksc : ksi) : (n < 512 ? qsc : qsi);
  u16* rp = buf + (long)row * 1024;
  const int t = threadIdx.x;
  const int h = t >> 4;           // head 0..15
  const int jj = (t & 15) * 2;    // rot index pair base 0..30
  const int e1 = h * 64 + jj;
  const int e2 = e1 + 32;
  uint32_t u1 = *(const uint32_t*)&rp[e1];
  uint32_t u2 = *(const uint32_t*)&rp[e2];
  float x1a = bf2f((u16)u1), x1b = bf2f((u16)(u1 >> 16));
  float x2a = bf2f((u16)u2), x2b = bf2f((u16)(u2 >> 16));
  float ss = x1a * x1a + x1b * x1b + x2a * x2a + x2b * x2b;
#pragma unroll
  for (int o = 32; o; o >>= 1) ss += __shfl_xor(ss, o, 64);
  if ((t & 63) == 0) sm[t >> 6] = ss;
  __syncthreads();
  ss = sm[0] + sm[1] + sm[2] + sm[3];
  const float rr = rsqrtf(ss * (1.0f / 1024.0f) + 1e-6f);
  float s1a = scale[e1], s1b = scale[e1 + 1], s2a = scale[e2], s2b = scale[e2 + 1];
  x1a *= rr * s1a; x1b *= rr * s1b; x2a *= rr * s2a; x2b *= rr * s2b;
  const float c = -13.287712379549449f / 32.0f;
  float fa = exp2f((float)jj * c), fb = exp2f((float)(jj + 1) * c);
  float sna, csa, snb, csb;
  sincosf((float)n * fa, &sna, &csa);
  sincosf((float)n * fb, &snb, &csb);
  u16 o1a = f2bf(x1a * csa - x2a * sna), o1b = f2bf(x1b * csb - x2b * snb);
  u16 o2a = f2bf(x2a * csa + x1a * sna), o2b = f2bf(x2b * csb + x1b * snb);
  *(uint32_t*)&rp[e1] = (uint32_t)o1a | ((uint32_t)o1b << 16);
  *(uint32_t*)&rp[e2] = (uint32_t)o2a | ((uint32_t)o2b << 16);
}

// ---------------- P_unnorm = exp((Q @ K^T) * 0.125)  (bf16 out, no max-sub) ----------------
// Single-buffer core (5 blocks/CU): grid 1296 fits ~one dispatch round at 5/CU.
__global__ __launch_bounds__(256, 5) void k_gemm_p(const u16* __restrict__ Q, const u16* __restrict__ Kb,
                                                   u16* __restrict__ P) {
  __shared__ u16 smem[16384];
  f32x4 acc[4][4] = {};
  long row0 = (long)blockIdx.x * 128;
  long col0 = (long)blockIdx.y * 128;
  gemm_sb64(Q, Kb, 1024, 1024, row0, col0, 0, 1024, smem, acc);
  EPI_VARS
#pragma unroll
  for (int mf = 0; mf < 4; ++mf)
#pragma unroll
    for (int nf = 0; nf < 4; ++nf)
#pragma unroll
      for (int r = 0; r < 4; ++r) {
        long m = row0 + wm * 64 + mf * 16 + mrow + r;
        long n = col0 + wn * 64 + nf * 16 + ncol;
        P[m * 4608 + n] = f2bf(__expf(acc[mf][nf][r] * 0.125f));
      }
}

// ---------------- row sums of P (deterministic): RS[row] = sum_n P[row][n] ----------------
__global__ __launch_bounds__(256) void k_rowsum(const u16* __restrict__ P, float* __restrict__ RS) {
  __shared__ float sm[4];
  const long row = blockIdx.x;
  const uint32_t* pr = (const uint32_t*)(P + row * 4608);   // 2304 u32 words
  const int t = threadIdx.x;
  float s = 0.f;
#pragma unroll
  for (int i = 0; i < 9; ++i) {
    uint32_t u = pr[i * 256 + t];
    s += bf2f((u16)u) + bf2f((u16)(u >> 16));
  }
#pragma unroll
  for (int o = 32; o; o >>= 1) s += __shfl_xor(s, o, 64);
  if ((t & 63) == 0) sm[t >> 6] = s;
  __syncthreads();
  if (t == 0) RS[row] = sm[0] + sm[1] + sm[2] + sm[3];
}

// ---------------- O partials = P @ V (split-K=3 over z), fp32 out ----------------
__global__ __launch_bounds__(256, 2) void k_gemm_o(const u16* __restrict__ P, const u16* __restrict__ VT,
                                                   float* __restrict__ OP) {
  __shared__ u16 smem[32768];
  f32x4 acc[4][4] = {};
  long row0 = (long)blockIdx.x * 128;
  long col0 = (long)blockIdx.y * 128;
  const int kc = blockIdx.z;           // 0..2, K chunk of 1536 (=24 tiles of 64)
  gemm_bk64(P, VT, 4608, 4608, row0, col0, kc * 1536, (kc + 1) * 1536, smem, acc);
  float* op = OP + (long)kc * 4608 * 1024;
  EPI_VARS
#pragma unroll
  for (int mf = 0; mf < 4; ++mf)
#pragma unroll
    for (int nf = 0; nf < 4; ++nf)
#pragma unroll
      for (int r = 0; r < 4; ++r) {
        long m = row0 + wm * 64 + mf * 16 + mrow + r;
        long n = col0 + wn * 64 + nf * 16 + ncol;
        op[m * 1024 + n] = acc[mf][nf][r];
      }
}

// ---------------- reduce 3 fp32 partials, divide by row sum -> bf16 AO ----------------
__global__ __launch_bounds__(256) void k_reduce3div(const float* __restrict__ OP,
                                                    const float* __restrict__ RS,
                                                    u16* __restrict__ AO) {
  const long st = 4608L * 1024;
  long i = ((long)blockIdx.x * 256 + threadIdx.x) * 4;
  const float inv = 1.0f / RS[i >> 10];           // 4 consecutive elems share a row
  float4 a = *(const float4*)&OP[i];
  float4 b = *(const float4*)&OP[i + st];
  float4 c = *(const float4*)&OP[i + 2 * st];
  ushort4 o;
  o.x = f2bf((a.x + b.x + c.x) * inv);
  o.y = f2bf((a.y + b.y + c.y) * inv);
  o.z = f2bf((a.z + b.z + c.z) * inv);
  o.w = f2bf((a.w + b.w + c.w) * inv);
  *(ushort4*)&AO[i] = o;
}

// ---------------- merged output projections: out = AO @ W^T + b (fp32 out) ----------------
__global__ __launch_bounds__(256, 2) void k_gemm_out2(const u16* __restrict__ AO,
                                                      const u16* __restrict__ WOI, const u16* __restrict__ WOC,
                                                      const float* __restrict__ boi, const float* __restrict__ boc,
                                                      float* __restrict__ out) {
  __shared__ u16 smem[32768];
  f32x4 acc[4][4] = {};
  long row0 = (long)blockIdx.x * 128;      // global row in [0,9216)
  long col0 = (long)blockIdx.y * 128;
  int b = (int)(row0 / 4608);
  int s0 = (int)(row0 % 4608);
  const bool ctx = s0 < 512;               // 512 % 128 == 0 -> uniform per block
  const u16* W = ctx ? WOC : WOI;
  const float* bias = ctx ? boc : boi;
  float* ob = ctx ? out + 8388608 + ((long)b * 512 + s0) * 1024
                  : out + ((long)b * 4096 + (s0 - 512)) * 1024;
  gemm_bk64(AO, W, 1024, 1024, row0, col0, 0, 1024, smem, acc);
  EPI_VARS
#pragma unroll
  for (int mf = 0; mf < 4; ++mf)
#pragma unroll
    for (int nf = 0; nf < 4; ++nf)
#pragma unroll
      for (int r = 0; r < 4; ++r) {
        long m = wm * 64 + mf * 16 + mrow + r;        // local row within tile
        long n = col0 + wn * 64 + nf * 16 + ncol;
        ob[m * 1024 + n] = acc[mf][nf][r] + bias[n];
      }
}

// ---------------- launch ----------------
extern "C" void kernel_launch(void* const* d_in, const int* in_sizes, int n_in,
                              void* d_out, int out_size, void* d_ws, size_t ws_size,
                              hipStream_t stream) {
  const float* input   = (const float*)d_in[0];
  const float* context = (const float*)d_in[1];
  const float* Wqi     = (const float*)d_in[2];
  const float* bqi     = (const float*)d_in[3];
  const float* Wqc     = (const float*)d_in[4];
  const float* bqc     = (const float*)d_in[5];
  const float* qsi     = (const float*)d_in[6];
  const float* ksi     = (const float*)d_in[7];
  const float* qsc     = (const float*)d_in[8];
  const float* ksc     = (const float*)d_in[9];
  const float* Woi     = (const float*)d_in[10];
  const float* boi     = (const float*)d_in[11];
  const float* Woc     = (const float*)d_in[12];
  const float* boc     = (const float*)d_in[13];
  float* out = (float*)d_out;

  uint8_t* ws = (uint8_t*)d_ws;
  // workspace layout (bytes)
  u16* XIN  = (u16*)(ws + 0);            // 2*4096*1024 bf16       = 16,777,216
  u16* XCTX = (u16*)(ws + 16777216);     // 2*512*1024             =  2,097,152
  u16* WQI  = (u16*)(ws + 18874368);     // 3072*1024              =  6,291,456
  u16* WQC  = (u16*)(ws + 25165824);     // 3072*1024              =  6,291,456
  u16* WOI  = (u16*)(ws + 31457280);     // 1024*1024              =  2,097,152
  u16* WOC  = (u16*)(ws + 33554432);     // 1024*1024              =  2,097,152
  u16* QB   = (u16*)(ws + 35651584);     // 2*4608*1024            = 18,874,368
  u16* KB   = (u16*)(ws + 54525952);     // 2*4608*1024            = 18,874,368
  u16* VT   = (u16*)(ws + 73400320);     // 2*1024*4608            = 18,874,368
  u16* AO   = (u16*)(ws + 92274688);     // 2*4608*1024            = 18,874,368
  float* S32 = (float*)(ws + 111149056); // region: 3x fp32 O-partials (56,623,104) + RS tail
  float* RS  = (float*)(ws + 186646528); // 4608 fp32 row sums (tail of S32 region)
  u16* PB   = (u16*)(ws + 196083712);    // 4608*4608 bf16 (per-batch, reused) = 42,467,328
  // total = 238,551,040 bytes

  // fp32 -> bf16 conversions (single launch)
  k_conv_all<<<dim3(17408), 256, 0, stream>>>(input, XIN, context, XCTX, Wqi, WQI,
                                              Wqc, WQC, Woi, WOI, Woc, WOC);

  // QKV projections, input (bx 0..63) + context (bx 64..71) in one launch
  k_gemm_qkv<<<dim3(72, 24), 256, 0, stream>>>(XIN, XCTX, WQI, WQC, bqi, bqc, QB, KB, VT);

  // RMSNorm + RoPE in place on q,k
  k_normrope<<<dim3(9216, 2), 256, 0, stream>>>(QB, KB, qsi, ksi, qsc, ksc);

  // attention, one batch at a time (P buffer reused; O-partials alias S32)
  for (int b = 0; b < 2; ++b) {
    const u16* Qb  = QB + (long)b * 4608 * 1024;
    const u16* Kbp = KB + (long)b * 4608 * 1024;
    const u16* VTb = VT + (long)b * 1024 * 4608;
    u16* AOb = AO + (long)b * 4608 * 1024;
    k_gemm_p<<<dim3(36, 36), 256, 0, stream>>>(Qb, Kbp, PB);
    k_rowsum<<<dim3(4608), 256, 0, stream>>>(PB, RS);
    k_gemm_o<<<dim3(36, 8, 3), 256, 0, stream>>>(PB, VTb, (float*)S32);
    k_reduce3div<<<dim3(4608), 256, 0, stream>>>((const float*)S32, RS, AOb);
  }

  // merged output projections
  k_gemm_out2<<<dim3(72, 8), 256, 0, stream>>>(AO, WOI, WOC, boi, boc, out);
}

// Round 15
// 441.325 us; speedup vs baseline: 1.5370x; 1.5370x over previous
//
#include <hip/hip_runtime.h>
#include <stdint.h>

typedef unsigned short u16;
typedef __bf16 bf16x8 __attribute__((ext_vector_type(8)));
typedef float f32x4 __attribute__((ext_vector_type(4)));

typedef const __attribute__((address_space(1))) uint32_t* gu32p;
typedef __attribute__((address_space(3))) uint32_t* lu32p;
#define GLOAD_LDS16(g, l) \
  __builtin_amdgcn_global_load_lds((gu32p)(const void*)(g), (lu32p)(void*)(l), 16, 0, 0)

static __device__ __forceinline__ u16 f2bf(float f) {
  uint32_t u = __builtin_bit_cast(uint32_t, f);
  return (u16)((u + 0x7FFFu + ((u >> 16) & 1u)) >> 16);
}
static __device__ __forceinline__ float bf2f(u16 h) {
  uint32_t u = ((uint32_t)h) << 16;
  return __builtin_bit_cast(float, u);
}

// ---------------- fused fp32 -> bf16 conversion (all 6 regions, 1 launch) ----------------
__global__ __launch_bounds__(256) void k_conv_all(
    const float* __restrict__ s0, u16* __restrict__ d0,   // input   8M elems, blocks [0,8192)
    const float* __restrict__ s1, u16* __restrict__ d1,   // context 1M, [8192,9216)
    const float* __restrict__ s2, u16* __restrict__ d2,   // Wqi     3M, [9216,12288)
    const float* __restrict__ s3, u16* __restrict__ d3,   // Wqc     3M, [12288,15360)
    const float* __restrict__ s4, u16* __restrict__ d4,   // Woi     1M, [15360,16384)
    const float* __restrict__ s5, u16* __restrict__ d5) { // Woc     1M, [16384,17408)
  int b = blockIdx.x;
  const float* src; u16* dst; long off;
  if (b < 8192)       { src = s0; dst = d0; off = (long)b * 1024; }
  else if (b < 9216)  { src = s1; dst = d1; off = (long)(b - 8192) * 1024; }
  else if (b < 12288) { src = s2; dst = d2; off = (long)(b - 9216) * 1024; }
  else if (b < 15360) { src = s3; dst = d3; off = (long)(b - 12288) * 1024; }
  else if (b < 16384) { src = s4; dst = d4; off = (long)(b - 15360) * 1024; }
  else                { src = s5; dst = d5; off = (long)(b - 16384) * 1024; }
  long i = off + threadIdx.x * 4;
  const float4 v = *(const float4*)&src[i];
  ushort4 o;
  o.x = f2bf(v.x); o.y = f2bf(v.y); o.z = f2bf(v.z); o.w = f2bf(v.w);
  *(ushort4*)&dst[i] = o;
}

// ---------------- 128x128 MFMA tile core, BK=64, swizzled, 2-dbuf (r12 best) ----------------
// 256 threads = 4 waves (2M x 2N); per-wave 64x64 = acc[4][4]. LDS 64 KiB -> 2 blocks/CU.
// Swizzle: LDS 16B-slot L of row r holds global slot L^(r&7) (involution; 0 conflicts).
__device__ __forceinline__ void gemm_bk64(const u16* __restrict__ A, const u16* __restrict__ Bt,
                                          int lda, int ldb, long row0, long col0,
                                          int kbeg, int kend, u16* smem, f32x4 acc[4][4]) {
  const int tid = threadIdx.x;
  const int l = tid & 63;
  const int w = tid >> 6;
  const int wm = w >> 1, wn = w & 1;
  const int lr = l & 15, kg = l >> 4;
  const int swz = (lr & 7) * 8;                    // read-side XOR (elems)
  const int r_l = tid >> 3;                        // 0..31
  const int ssrc = ((tid & 7) ^ (r_l & 7)) * 8;    // pre-swizzled source col (elems)
  const u16* gA = &A[(row0 + r_l) * (long)lda + ssrc];
  const u16* gB = &Bt[(col0 + r_l) * (long)ldb + ssrc];
  u16* const ldsA = smem + w * 512;                // wave-uniform bases (elems)
  u16* const ldsB = smem + 8192 + w * 512;
  const int NT = (kend - kbeg) >> 6;

  { // prologue: tile 0 -> dbuf 0
#pragma unroll
    for (int c = 0; c < 4; ++c) {
      GLOAD_LDS16(gA + (c * 32) * (long)lda + kbeg, ldsA + c * 2048);
      GLOAD_LDS16(gB + (c * 32) * (long)ldb + kbeg, ldsB + c * 2048);
    }
  }
  asm volatile("s_waitcnt vmcnt(0)" ::: "memory");
  __builtin_amdgcn_s_barrier();
  __builtin_amdgcn_sched_barrier(0);

  for (int t = 0; t < NT; ++t) {
    const int d = (t & 1) << 14;                   // dbuf offset (elems)
    const int dn = ((t + 1) & 1) << 14;
    const bool pf = (t + 1 < NT);
    const long k1 = kbeg + (long)(t + 1) * 64;
    bf16x8 af[4], bv[4];
    // ---- phase 0: stage A(t+1); compute k-step s=0 ----
    if (pf) {
#pragma unroll
      for (int c = 0; c < 4; ++c)
        GLOAD_LDS16(gA + (c * 32) * (long)lda + k1, ldsA + dn + c * 2048);
    }
#pragma unroll
    for (int i = 0; i < 4; ++i) {
      af[i] = *(const bf16x8*)&smem[d + (wm * 64 + i * 16 + lr) * 64 + (kg * 8 ^ swz)];
      bv[i] = *(const bf16x8*)&smem[d + 8192 + (wn * 64 + i * 16 + lr) * 64 + (kg * 8 ^ swz)];
    }
    __builtin_amdgcn_s_setprio(1);
#pragma unroll
    for (int mf = 0; mf < 4; ++mf)
#pragma unroll
      for (int nf = 0; nf < 4; ++nf)
        acc[mf][nf] = __builtin_amdgcn_mfma_f32_16x16x32_bf16(af[mf], bv[nf], acc[mf][nf], 0, 0, 0);
    __builtin_amdgcn_s_setprio(0);
    // ---- phase 1: stage B(t+1); compute k-step s=1 ----
    if (pf) {
#pragma unroll
      for (int c = 0; c < 4; ++c)
        GLOAD_LDS16(gB + (c * 32) * (long)ldb + k1, ldsB + dn + c * 2048);
    }
#pragma unroll
    for (int i = 0; i < 4; ++i) {
      af[i] = *(const bf16x8*)&smem[d + (wm * 64 + i * 16 + lr) * 64 + ((32 + kg * 8) ^ swz)];
      bv[i] = *(const bf16x8*)&smem[d + 8192 + (wn * 64 + i * 16 + lr) * 64 + ((32 + kg * 8) ^ swz)];
    }
    __builtin_amdgcn_s_setprio(1);
#pragma unroll
    for (int mf = 0; mf < 4; ++mf)
#pragma unroll
      for (int nf = 0; nf < 4; ++nf)
        acc[mf][nf] = __builtin_amdgcn_mfma_f32_16x16x32_bf16(af[mf], bv[nf], acc[mf][nf], 0, 0, 0);
    __builtin_amdgcn_s_setprio(0);
    asm volatile("s_waitcnt vmcnt(0)" ::: "memory");  // t+1 stage landed; mostly shadowed
    __builtin_amdgcn_s_barrier();
    __builtin_amdgcn_sched_barrier(0);
  }
}

#define EPI_VARS                                   \
  const int l = threadIdx.x & 63;                  \
  const int w = threadIdx.x >> 6;                  \
  const int wm = w >> 1, wn = w & 1;               \
  const int mrow = (l >> 4) * 4, ncol = l & 15;

// ---------------- QKV projection (input + context merged) ----------------
__global__ __launch_bounds__(256, 2) void k_gemm_qkv(
    const u16* __restrict__ XIN, const u16* __restrict__ XCTX,
    const u16* __restrict__ WQI, const u16* __restrict__ WQC,
    const float* __restrict__ bqi, const float* __restrict__ bqc,
    u16* __restrict__ qb, u16* __restrict__ kb, u16* __restrict__ vt) {
  __shared__ u16 smem[32768];
  f32x4 acc[4][4] = {};
  const bool isCtx = blockIdx.x >= 64;
  const u16* X = isCtx ? XCTX : XIN;
  const u16* W = isCtx ? WQC : WQI;
  const float* bias = isCtx ? bqc : bqi;
  const int seg_start = isCtx ? 0 : 512;
  long row0 = (long)(isCtx ? blockIdx.x - 64 : blockIdx.x) * 128;
  long col0 = (long)blockIdx.y * 128;
  gemm_bk64(X, W, 1024, 1024, row0, col0, 0, 1024, smem, acc);
  EPI_VARS
#pragma unroll
  for (int mf = 0; mf < 4; ++mf)
#pragma unroll
    for (int nf = 0; nf < 4; ++nf)
#pragma unroll
      for (int r = 0; r < 4; ++r) {
        int m = (int)row0 + wm * 64 + mf * 16 + mrow + r;
        int n = (int)col0 + wn * 64 + nf * 16 + ncol;
        float v = acc[mf][nf][r] + bias[n];
        int b, s;
        if (isCtx) { b = m >> 9; s = m & 511; } else { b = m >> 12; s = m & 4095; }
        long grow = (long)b * 4608 + seg_start + s;
        if (n < 1024)      qb[grow * 1024 + n] = f2bf(v);
        else if (n < 2048) kb[grow * 1024 + (n - 1024)] = f2bf(v);
        else               vt[((long)b * 1024 + (n - 2048)) * 4608 + seg_start + s] = f2bf(v);
      }
}

// ---------------- RMSNorm + RoPE (in-place on q_buf / k_buf), vectorized ----------------
__global__ __launch_bounds__(256) void k_normrope(u16* __restrict__ qb, u16* __restrict__ kb,
                                                  const float* __restrict__ qsi, const float* __restrict__ ksi,
                                                  const float* __restrict__ qsc, const float* __restrict__ ksc) {
  __shared__ float sm[4];
  const int row = blockIdx.x;    // 0..9215  (b*4608 + n)
  const int which = blockIdx.y;  // 0 = q, 1 = k
  const int n = row % 4608;
  u16* buf = which ? kb : qb;
  const float* scale = which ? (n < 512 ? ksc : ksi) : (n < 512 ? qsc : qsi);
  u16* rp = buf + (long)row * 1024;
  const int t = threadIdx.x;
  const int h = t >> 4;           // head 0..15
  const int jj = (t & 15) * 2;    // rot index pair base 0..30
  const int e1 = h * 64 + jj;
  const int e2 = e1 + 32;
  uint32_t u1 = *(const uint32_t*)&rp[e1];
  uint32_t u2 = *(const uint32_t*)&rp[e2];
  float x1a = bf2f((u16)u1), x1b = bf2f((u16)(u1 >> 16));
  float x2a = bf2f((u16)u2), x2b = bf2f((u16)(u2 >> 16));
  float ss = x1a * x1a + x1b * x1b + x2a * x2a + x2b * x2b;
#pragma unroll
  for (int o = 32; o; o >>= 1) ss += __shfl_xor(ss, o, 64);
  if ((t & 63) == 0) sm[t >> 6] = ss;
  __syncthreads();
  ss = sm[0] + sm[1] + sm[2] + sm[3];
  const float rr = rsqrtf(ss * (1.0f / 1024.0f) + 1e-6f);
  float s1a = scale[e1], s1b = scale[e1 + 1], s2a = scale[e2], s2b = scale[e2 + 1];
  x1a *= rr * s1a; x1b *= rr * s1b; x2a *= rr * s2a; x2b *= rr * s2b;
  const float c = -13.287712379549449f / 32.0f;
  float fa = exp2f((float)jj * c), fb = exp2f((float)(jj + 1) * c);
  float sna, csa, snb, csb;
  sincosf((float)n * fa, &sna, &csa);
  sincosf((float)n * fb, &snb, &csb);
  u16 o1a = f2bf(x1a * csa - x2a * sna), o1b = f2bf(x1b * csb - x2b * snb);
  u16 o2a = f2bf(x2a * csa + x1a * sna), o2b = f2bf(x2b * csb + x1b * snb);
  *(uint32_t*)&rp[e1] = (uint32_t)o1a | ((uint32_t)o1b << 16);
  *(uint32_t*)&rp[e2] = (uint32_t)o2a | ((uint32_t)o2b << 16);
}

// ---------------- P_unnorm = exp((Q @ K^T) * 0.125)  (bf16 out, no max-sub) ----------------
// Safe: scores ~ N(0,16); max over 42M samples ~ 24 << 88 (expf overflow). Normalization
// happens in k_reduce2div using row sums of the SAME bf16-rounded P (k_rowsum).
__global__ __launch_bounds__(256, 2) void k_gemm_p(const u16* __restrict__ Q, const u16* __restrict__ Kb,
                                                   u16* __restrict__ P) {
  __shared__ u16 smem[32768];
  f32x4 acc[4][4] = {};
  long row0 = (long)blockIdx.x * 128;
  long col0 = (long)blockIdx.y * 128;
  gemm_bk64(Q, Kb, 1024, 1024, row0, col0, 0, 1024, smem, acc);
  EPI_VARS
#pragma unroll
  for (int mf = 0; mf < 4; ++mf)
#pragma unroll
    for (int nf = 0; nf < 4; ++nf)
#pragma unroll
      for (int r = 0; r < 4; ++r) {
        long m = row0 + wm * 64 + mf * 16 + mrow + r;
        long n = col0 + wn * 64 + nf * 16 + ncol;
        P[m * 4608 + n] = f2bf(__expf(acc[mf][nf][r] * 0.125f));
      }
}

// ---------------- row sums of P (deterministic): RS[row] = sum_n P[row][n] ----------------
__global__ __launch_bounds__(256) void k_rowsum(const u16* __restrict__ P, float* __restrict__ RS) {
  __shared__ float sm[4];
  const long row = blockIdx.x;
  const uint32_t* pr = (const uint32_t*)(P + row * 4608);   // 2304 u32 words
  const int t = threadIdx.x;
  float s = 0.f;
#pragma unroll
  for (int i = 0; i < 9; ++i) {
    uint32_t u = pr[i * 256 + t];
    s += bf2f((u16)u) + bf2f((u16)(u >> 16));
  }
#pragma unroll
  for (int o = 32; o; o >>= 1) s += __shfl_xor(s, o, 64);
  if ((t & 63) == 0) sm[t >> 6] = s;
  __syncthreads();
  if (t == 0) RS[row] = sm[0] + sm[1] + sm[2] + sm[3];
}

// ---------------- O partials = P @ V (split-K=2 over z), fp32 out ----------------
__global__ __launch_bounds__(256, 2) void k_gemm_o(const u16* __restrict__ P, const u16* __restrict__ VT,
                                                   float* __restrict__ OP) {
  __shared__ u16 smem[32768];
  f32x4 acc[4][4] = {};
  long row0 = (long)blockIdx.x * 128;
  long col0 = (long)blockIdx.y * 128;
  const int kc = blockIdx.z;           // 0..1, K chunk of 2304 (=36 tiles of 64)
  gemm_bk64(P, VT, 4608, 4608, row0, col0, kc * 2304, (kc + 1) * 2304, smem, acc);
  float* op = OP + (long)kc * 4608 * 1024;
  EPI_VARS
#pragma unroll
  for (int mf = 0; mf < 4; ++mf)
#pragma unroll
    for (int nf = 0; nf < 4; ++nf)
#pragma unroll
      for (int r = 0; r < 4; ++r) {
        long m = row0 + wm * 64 + mf * 16 + mrow + r;
        long n = col0 + wn * 64 + nf * 16 + ncol;
        op[m * 1024 + n] = acc[mf][nf][r];
      }
}

// ---------------- reduce 2 fp32 partials, divide by row sum -> bf16 AO ----------------
__global__ __launch_bounds__(256) void k_reduce2div(const float* __restrict__ OP,
                                                    const float* __restrict__ RS,
                                                    u16* __restrict__ AO) {
  const long st = 4608L * 1024;
  long i = ((long)blockIdx.x * 256 + threadIdx.x) * 4;
  const float inv = 1.0f / RS[i >> 10];           // 4 consecutive elems share a row
  float4 a = *(const float4*)&OP[i];
  float4 b = *(const float4*)&OP[i + st];
  ushort4 o;
  o.x = f2bf((a.x + b.x) * inv);
  o.y = f2bf((a.y + b.y) * inv);
  o.z = f2bf((a.z + b.z) * inv);
  o.w = f2bf((a.w + b.w) * inv);
  *(ushort4*)&AO[i] = o;
}

// ---------------- merged output projections: out = AO @ W^T + b (fp32 out) ----------------
__global__ __launch_bounds__(256, 2) void k_gemm_out2(const u16* __restrict__ AO,
                                                      const u16* __restrict__ WOI, const u16* __restrict__ WOC,
                                                      const float* __restrict__ boi, const float* __restrict__ boc,
                                                      float* __restrict__ out) {
  __shared__ u16 smem[32768];
  f32x4 acc[4][4] = {};
  long row0 = (long)blockIdx.x * 128;      // global row in [0,9216)
  long col0 = (long)blockIdx.y * 128;
  int b = (int)(row0 / 4608);
  int s0 = (int)(row0 % 4608);
  const bool ctx = s0 < 512;               // 512 % 128 == 0 -> uniform per block
  const u16* W = ctx ? WOC : WOI;
  const float* bias = ctx ? boc : boi;
  float* ob = ctx ? out + 8388608 + ((long)b * 512 + s0) * 1024
                  : out + ((long)b * 4096 + (s0 - 512)) * 1024;
  gemm_bk64(AO, W, 1024, 1024, row0, col0, 0, 1024, smem, acc);
  EPI_VARS
#pragma unroll
  for (int mf = 0; mf < 4; ++mf)
#pragma unroll
    for (int nf = 0; nf < 4; ++nf)
#pragma unroll
      for (int r = 0; r < 4; ++r) {
        long m = wm * 64 + mf * 16 + mrow + r;        // local row within tile
        long n = col0 + wn * 64 + nf * 16 + ncol;
        ob[m * 1024 + n] = acc[mf][nf][r] + bias[n];
      }
}

// ---------------- launch ----------------
extern "C" void kernel_launch(void* const* d_in, const int* in_sizes, int n_in,
                              void* d_out, int out_size, void* d_ws, size_t ws_size,
                              hipStream_t stream) {
  const float* input   = (const float*)d_in[0];
  const float* context = (const float*)d_in[1];
  const float* Wqi     = (const float*)d_in[2];
  const float* bqi     = (const float*)d_in[3];
  const float* Wqc     = (const float*)d_in[4];
  const float* bqc     = (const float*)d_in[5];
  const float* qsi     = (const float*)d_in[6];
  const float* ksi     = (const float*)d_in[7];
  const float* qsc     = (const float*)d_in[8];
  const float* ksc     = (const float*)d_in[9];
  const float* Woi     = (const float*)d_in[10];
  const float* boi     = (const float*)d_in[11];
  const float* Woc     = (const float*)d_in[12];
  const float* boc     = (const float*)d_in[13];
  float* out = (float*)d_out;

  uint8_t* ws = (uint8_t*)d_ws;
  // workspace layout (bytes)
  u16* XIN  = (u16*)(ws + 0);            // 2*4096*1024 bf16       = 16,777,216
  u16* XCTX = (u16*)(ws + 16777216);     // 2*512*1024             =  2,097,152
  u16* WQI  = (u16*)(ws + 18874368);     // 3072*1024              =  6,291,456
  u16* WQC  = (u16*)(ws + 25165824);     // 3072*1024              =  6,291,456
  u16* WOI  = (u16*)(ws + 31457280);     // 1024*1024              =  2,097,152
  u16* WOC  = (u16*)(ws + 33554432);     // 1024*1024              =  2,097,152
  u16* QB   = (u16*)(ws + 35651584);     // 2*4608*1024            = 18,874,368
  u16* KB   = (u16*)(ws + 54525952);     // 2*4608*1024            = 18,874,368
  u16* VT   = (u16*)(ws + 73400320);     // 2*1024*4608            = 18,874,368
  u16* AO   = (u16*)(ws + 92274688);     // 2*4608*1024            = 18,874,368
  float* S32 = (float*)(ws + 111149056); // region: 2x fp32 O-partials (75,497,472) + RS tail
  float* RS  = (float*)(ws + 186646528); // 4608 fp32 row sums (tail of S32 region)
  u16* PB   = (u16*)(ws + 196083712);    // 4608*4608 bf16 (per-batch, reused) = 42,467,328
  // total = 238,551,040 bytes

  // fp32 -> bf16 conversions (single launch)
  k_conv_all<<<dim3(17408), 256, 0, stream>>>(input, XIN, context, XCTX, Wqi, WQI,
                                              Wqc, WQC, Woi, WOI, Woc, WOC);

  // QKV projections, input (bx 0..63) + context (bx 64..71) in one launch
  k_gemm_qkv<<<dim3(72, 24), 256, 0, stream>>>(XIN, XCTX, WQI, WQC, bqi, bqc, QB, KB, VT);

  // RMSNorm + RoPE in place on q,k
  k_normrope<<<dim3(9216, 2), 256, 0, stream>>>(QB, KB, qsi, ksi, qsc, ksc);

  // attention, one batch at a time (P buffer reused; O-partials alias S32)
  for (int b = 0; b < 2; ++b) {
    const u16* Qb  = QB + (long)b * 4608 * 1024;
    const u16* Kbp = KB + (long)b * 4608 * 1024;
    const u16* VTb = VT + (long)b * 1024 * 4608;
    u16* AOb = AO + (long)b * 4608 * 1024;
    k_gemm_p<<<dim3(36, 36), 256, 0, stream>>>(Qb, Kbp, PB);
    k_rowsum<<<dim3(4608), 256, 0, stream>>>(PB, RS);
    k_gemm_o<<<dim3(36, 8, 2), 256, 0, stream>>>(PB, VTb, (float*)S32);
    k_reduce2div<<<dim3(4608), 256, 0, stream>>>((const float*)S32, RS, AOb);
  }

  // merged output projections
  k_gemm_out2<<<dim3(72, 8), 256, 0, stream>>>(AO, WOI, WOC, boi, boc, out);
}

// Round 16
// 439.375 us; speedup vs baseline: 1.5438x; 1.0044x over previous
//
#include <hip/hip_runtime.h>
#include <stdint.h>

typedef unsigned short u16;
typedef __bf16 bf16x8 __attribute__((ext_vector_type(8)));
typedef float f32x4 __attribute__((ext_vector_type(4)));

typedef const __attribute__((address_space(1))) uint32_t* gu32p;
typedef __attribute__((address_space(3))) uint32_t* lu32p;
#define GLOAD_LDS16(g, l) \
  __builtin_amdgcn_global_load_lds((gu32p)(const void*)(g), (lu32p)(void*)(l), 16, 0, 0)

static __device__ __forceinline__ u16 f2bf(float f) {
  uint32_t u = __builtin_bit_cast(uint32_t, f);
  return (u16)((u + 0x7FFFu + ((u >> 16) & 1u)) >> 16);
}
static __device__ __forceinline__ float bf2f(u16 h) {
  uint32_t u = ((uint32_t)h) << 16;
  return __builtin_bit_cast(float, u);
}

// ---------------- fused fp32 -> bf16 conversion (all 6 regions, 1 launch) ----------------
__global__ __launch_bounds__(256) void k_conv_all(
    const float* __restrict__ s0, u16* __restrict__ d0,   // input   8M elems, blocks [0,8192)
    const float* __restrict__ s1, u16* __restrict__ d1,   // context 1M, [8192,9216)
    const float* __restrict__ s2, u16* __restrict__ d2,   // Wqi     3M, [9216,12288)
    const float* __restrict__ s3, u16* __restrict__ d3,   // Wqc     3M, [12288,15360)
    const float* __restrict__ s4, u16* __restrict__ d4,   // Woi     1M, [15360,16384)
    const float* __restrict__ s5, u16* __restrict__ d5) { // Woc     1M, [16384,17408)
  int b = blockIdx.x;
  const float* src; u16* dst; long off;
  if (b < 8192)       { src = s0; dst = d0; off = (long)b * 1024; }
  else if (b < 9216)  { src = s1; dst = d1; off = (long)(b - 8192) * 1024; }
  else if (b < 12288) { src = s2; dst = d2; off = (long)(b - 9216) * 1024; }
  else if (b < 15360) { src = s3; dst = d3; off = (long)(b - 12288) * 1024; }
  else if (b < 16384) { src = s4; dst = d4; off = (long)(b - 15360) * 1024; }
  else                { src = s5; dst = d5; off = (long)(b - 16384) * 1024; }
  long i = off + threadIdx.x * 4;
  const float4 v = *(const float4*)&src[i];
  ushort4 o;
  o.x = f2bf(v.x); o.y = f2bf(v.y); o.z = f2bf(v.z); o.w = f2bf(v.w);
  *(ushort4*)&dst[i] = o;
}

// ---------------- 128x128 MFMA tile core, BK=64, swizzled, 2-dbuf (r12 best) ----------------
// 256 threads = 4 waves (2M x 2N); per-wave 64x64 = acc[4][4]. LDS 64 KiB -> 2 blocks/CU.
// Swizzle: LDS 16B-slot L of row r holds global slot L^(r&7) (involution; 0 conflicts).
__device__ __forceinline__ void gemm_bk64(const u16* __restrict__ A, const u16* __restrict__ Bt,
                                          int lda, int ldb, long row0, long col0,
                                          int kbeg, int kend, u16* smem, f32x4 acc[4][4]) {
  const int tid = threadIdx.x;
  const int l = tid & 63;
  const int w = tid >> 6;
  const int wm = w >> 1, wn = w & 1;
  const int lr = l & 15, kg = l >> 4;
  const int swz = (lr & 7) * 8;                    // read-side XOR (elems)
  const int r_l = tid >> 3;                        // 0..31
  const int ssrc = ((tid & 7) ^ (r_l & 7)) * 8;    // pre-swizzled source col (elems)
  const u16* gA = &A[(row0 + r_l) * (long)lda + ssrc];
  const u16* gB = &Bt[(col0 + r_l) * (long)ldb + ssrc];
  u16* const ldsA = smem + w * 512;                // wave-uniform bases (elems)
  u16* const ldsB = smem + 8192 + w * 512;
  const int NT = (kend - kbeg) >> 6;

  { // prologue: tile 0 -> dbuf 0
#pragma unroll
    for (int c = 0; c < 4; ++c) {
      GLOAD_LDS16(gA + (c * 32) * (long)lda + kbeg, ldsA + c * 2048);
      GLOAD_LDS16(gB + (c * 32) * (long)ldb + kbeg, ldsB + c * 2048);
    }
  }
  asm volatile("s_waitcnt vmcnt(0)" ::: "memory");
  __builtin_amdgcn_s_barrier();
  __builtin_amdgcn_sched_barrier(0);

  for (int t = 0; t < NT; ++t) {
    const int d = (t & 1) << 14;                   // dbuf offset (elems)
    const int dn = ((t + 1) & 1) << 14;
    const bool pf = (t + 1 < NT);
    const long k1 = kbeg + (long)(t + 1) * 64;
    bf16x8 af[4], bv[4];
    // ---- phase 0: stage A(t+1); compute k-step s=0 ----
    if (pf) {
#pragma unroll
      for (int c = 0; c < 4; ++c)
        GLOAD_LDS16(gA + (c * 32) * (long)lda + k1, ldsA + dn + c * 2048);
    }
#pragma unroll
    for (int i = 0; i < 4; ++i) {
      af[i] = *(const bf16x8*)&smem[d + (wm * 64 + i * 16 + lr) * 64 + (kg * 8 ^ swz)];
      bv[i] = *(const bf16x8*)&smem[d + 8192 + (wn * 64 + i * 16 + lr) * 64 + (kg * 8 ^ swz)];
    }
    __builtin_amdgcn_s_setprio(1);
#pragma unroll
    for (int mf = 0; mf < 4; ++mf)
#pragma unroll
      for (int nf = 0; nf < 4; ++nf)
        acc[mf][nf] = __builtin_amdgcn_mfma_f32_16x16x32_bf16(af[mf], bv[nf], acc[mf][nf], 0, 0, 0);
    __builtin_amdgcn_s_setprio(0);
    // ---- phase 1: stage B(t+1); compute k-step s=1 ----
    if (pf) {
#pragma unroll
      for (int c = 0; c < 4; ++c)
        GLOAD_LDS16(gB + (c * 32) * (long)ldb + k1, ldsB + dn + c * 2048);
    }
#pragma unroll
    for (int i = 0; i < 4; ++i) {
      af[i] = *(const bf16x8*)&smem[d + (wm * 64 + i * 16 + lr) * 64 + ((32 + kg * 8) ^ swz)];
      bv[i] = *(const bf16x8*)&smem[d + 8192 + (wn * 64 + i * 16 + lr) * 64 + ((32 + kg * 8) ^ swz)];
    }
    __builtin_amdgcn_s_setprio(1);
#pragma unroll
    for (int mf = 0; mf < 4; ++mf)
#pragma unroll
      for (int nf = 0; nf < 4; ++nf)
        acc[mf][nf] = __builtin_amdgcn_mfma_f32_16x16x32_bf16(af[mf], bv[nf], acc[mf][nf], 0, 0, 0);
    __builtin_amdgcn_s_setprio(0);
    asm volatile("s_waitcnt vmcnt(0)" ::: "memory");  // t+1 stage landed; mostly shadowed
    __builtin_amdgcn_s_barrier();
    __builtin_amdgcn_sched_barrier(0);
  }
}

#define EPI_VARS                                   \
  const int l = threadIdx.x & 63;                  \
  const int w = threadIdx.x >> 6;                  \
  const int wm = w >> 1, wn = w & 1;               \
  const int mrow = (l >> 4) * 4, ncol = l & 15;

// ---------------- QKV projection (input + context merged) ----------------
__global__ __launch_bounds__(256, 2) void k_gemm_qkv(
    const u16* __restrict__ XIN, const u16* __restrict__ XCTX,
    const u16* __restrict__ WQI, const u16* __restrict__ WQC,
    const float* __restrict__ bqi, const float* __restrict__ bqc,
    u16* __restrict__ qb, u16* __restrict__ kb, u16* __restrict__ vt) {
  __shared__ u16 smem[32768];
  f32x4 acc[4][4] = {};
  const bool isCtx = blockIdx.x >= 64;
  const u16* X = isCtx ? XCTX : XIN;
  const u16* W = isCtx ? WQC : WQI;
  const float* bias = isCtx ? bqc : bqi;
  const int seg_start = isCtx ? 0 : 512;
  long row0 = (long)(isCtx ? blockIdx.x - 64 : blockIdx.x) * 128;
  long col0 = (long)blockIdx.y * 128;
  gemm_bk64(X, W, 1024, 1024, row0, col0, 0, 1024, smem, acc);
  EPI_VARS
#pragma unroll
  for (int mf = 0; mf < 4; ++mf)
#pragma unroll
    for (int nf = 0; nf < 4; ++nf)
#pragma unroll
      for (int r = 0; r < 4; ++r) {
        int m = (int)row0 + wm * 64 + mf * 16 + mrow + r;
        int n = (int)col0 + wn * 64 + nf * 16 + ncol;
        float v = acc[mf][nf][r] + bias[n];
        int b, s;
        if (isCtx) { b = m >> 9; s = m & 511; } else { b = m >> 12; s = m & 4095; }
        long grow = (long)b * 4608 + seg_start + s;
        if (n < 1024)      qb[grow * 1024 + n] = f2bf(v);
        else if (n < 2048) kb[grow * 1024 + (n - 1024)] = f2bf(v);
        else               vt[((long)b * 1024 + (n - 2048)) * 4608 + seg_start + s] = f2bf(v);
      }
}

// ---------------- RMSNorm + RoPE (in-place on q_buf / k_buf), vectorized ----------------
__global__ __launch_bounds__(256) void k_normrope(u16* __restrict__ qb, u16* __restrict__ kb,
                                                  const float* __restrict__ qsi, const float* __restrict__ ksi,
                                                  const float* __restrict__ qsc, const float* __restrict__ ksc) {
  __shared__ float sm[4];
  const int row = blockIdx.x;    // 0..9215  (b*4608 + n)
  const int which = blockIdx.y;  // 0 = q, 1 = k
  const int n = row % 4608;
  u16* buf = which ? kb : qb;
  const float* scale = which ? (n < 512 ? ksc : ksi) : (n < 512 ? qsc : qsi);
  u16* rp = buf + (long)row * 1024;
  const int t = threadIdx.x;
  const int h = t >> 4;           // head 0..15
  const int jj = (t & 15) * 2;    // rot index pair base 0..30
  const int e1 = h * 64 + jj;
  const int e2 = e1 + 32;
  uint32_t u1 = *(const uint32_t*)&rp[e1];
  uint32_t u2 = *(const uint32_t*)&rp[e2];
  float x1a = bf2f((u16)u1), x1b = bf2f((u16)(u1 >> 16));
  float x2a = bf2f((u16)u2), x2b = bf2f((u16)(u2 >> 16));
  float ss = x1a * x1a + x1b * x1b + x2a * x2a + x2b * x2b;
#pragma unroll
  for (int o = 32; o; o >>= 1) ss += __shfl_xor(ss, o, 64);
  if ((t & 63) == 0) sm[t >> 6] = ss;
  __syncthreads();
  ss = sm[0] + sm[1] + sm[2] + sm[3];
  const float rr = rsqrtf(ss * (1.0f / 1024.0f) + 1e-6f);
  float s1a = scale[e1], s1b = scale[e1 + 1], s2a = scale[e2], s2b = scale[e2 + 1];
  x1a *= rr * s1a; x1b *= rr * s1b; x2a *= rr * s2a; x2b *= rr * s2b;
  const float c = -13.287712379549449f / 32.0f;
  float fa = exp2f((float)jj * c), fb = exp2f((float)(jj + 1) * c);
  float sna, csa, snb, csb;
  sincosf((float)n * fa, &sna, &csa);
  sincosf((float)n * fb, &snb, &csb);
  u16 o1a = f2bf(x1a * csa - x2a * sna), o1b = f2bf(x1b * csb - x2b * snb);
  u16 o2a = f2bf(x2a * csa + x1a * sna), o2b = f2bf(x2b * csb + x1b * snb);
  *(uint32_t*)&rp[e1] = (uint32_t)o1a | ((uint32_t)o1b << 16);
  *(uint32_t*)&rp[e2] = (uint32_t)o2a | ((uint32_t)o2b << 16);
}

// ------- P_unnorm = exp((Q @ K^T) * 0.125) (bf16) + fused per-tile row partials -------
// No max-sub needed (scores ~ N(0,16), max << 88). Row partials of the SAME
// bf16-rounded P are reduced in-register (16-lane shfl tree) + via dead LDS,
// written to RSP[row][col_tile]; k_rsfin sums the 36 tiles -> RS. This replaces
// the k_rowsum pass (42.5 MB re-read of P per batch).
__global__ __launch_bounds__(256, 2) void k_gemm_p(const u16* __restrict__ Q, const u16* __restrict__ Kb,
                                                   u16* __restrict__ P, float* __restrict__ RSP) {
  __shared__ u16 smem[32768];
  f32x4 acc[4][4] = {};
  long row0 = (long)blockIdx.x * 128;
  long col0 = (long)blockIdx.y * 128;
  gemm_bk64(Q, Kb, 1024, 1024, row0, col0, 0, 1024, smem, acc);
  EPI_VARS
  float rowacc[16];
#pragma unroll
  for (int j = 0; j < 16; ++j) rowacc[j] = 0.f;
#pragma unroll
  for (int mf = 0; mf < 4; ++mf)
#pragma unroll
    for (int nf = 0; nf < 4; ++nf)
#pragma unroll
      for (int r = 0; r < 4; ++r) {
        long m = row0 + wm * 64 + mf * 16 + mrow + r;
        long n = col0 + wn * 64 + nf * 16 + ncol;
        u16 pb = f2bf(__expf(acc[mf][nf][r] * 0.125f));
        P[m * 4608 + n] = pb;
        rowacc[mf * 4 + r] += bf2f(pb);
      }
  // reduce across the 16 lanes (l&15) sharing each row (xor offsets stay in-group)
#pragma unroll
  for (int j = 0; j < 16; ++j) {
#pragma unroll
    for (int o = 1; o < 16; o <<= 1)
      rowacc[j] += __shfl_xor(rowacc[j], o, 64);
  }
  float* smf = (float*)smem;     // LDS dead after gemm loop (ends with s_barrier)
  if ((l & 15) == 0) {
#pragma unroll
    for (int mf = 0; mf < 4; ++mf)
#pragma unroll
      for (int r = 0; r < 4; ++r)
        smf[w * 64 + mf * 16 + mrow + r] = rowacc[mf * 4 + r];
  }
  __syncthreads();
  if (threadIdx.x < 128) {
    int i = threadIdx.x;
    int half = i >> 6;           // 0: rows 0-63 (waves 0+1), 1: rows 64-127 (waves 2+3)
    int lr2 = i & 63;
    float s = smf[half * 128 + lr2] + smf[half * 128 + 64 + lr2];
    RSP[(row0 + half * 64 + lr2) * 36 + blockIdx.y] = s;
  }
}

// ---------------- RS[row] = sum of 36 per-tile partials (deterministic) ----------------
__global__ __launch_bounds__(256) void k_rsfin(const float* __restrict__ RSP, float* __restrict__ RS) {
  int row = blockIdx.x * 256 + threadIdx.x;      // grid 18 -> 4608 rows
  const float* rp = RSP + (long)row * 36;
  float s = 0.f;
#pragma unroll
  for (int j = 0; j < 36; ++j) s += rp[j];
  RS[row] = s;
}

// ---------------- O partials = P @ V (split-K=2 over z), fp32 out ----------------
__global__ __launch_bounds__(256, 2) void k_gemm_o(const u16* __restrict__ P, const u16* __restrict__ VT,
                                                   float* __restrict__ OP) {
  __shared__ u16 smem[32768];
  f32x4 acc[4][4] = {};
  long row0 = (long)blockIdx.x * 128;
  long col0 = (long)blockIdx.y * 128;
  const int kc = blockIdx.z;           // 0..1, K chunk of 2304 (=36 tiles of 64)
  gemm_bk64(P, VT, 4608, 4608, row0, col0, kc * 2304, (kc + 1) * 2304, smem, acc);
  float* op = OP + (long)kc * 4608 * 1024;
  EPI_VARS
#pragma unroll
  for (int mf = 0; mf < 4; ++mf)
#pragma unroll
    for (int nf = 0; nf < 4; ++nf)
#pragma unroll
      for (int r = 0; r < 4; ++r) {
        long m = row0 + wm * 64 + mf * 16 + mrow + r;
        long n = col0 + wn * 64 + nf * 16 + ncol;
        op[m * 1024 + n] = acc[mf][nf][r];
      }
}

// ---------------- reduce 2 fp32 partials, divide by row sum -> bf16 AO ----------------
__global__ __launch_bounds__(256) void k_reduce2div(const float* __restrict__ OP,
                                                    const float* __restrict__ RS,
                                                    u16* __restrict__ AO) {
  const long st = 4608L * 1024;
  long i = ((long)blockIdx.x * 256 + threadIdx.x) * 4;
  const float inv = 1.0f / RS[i >> 10];           // 4 consecutive elems share a row
  float4 a = *(const float4*)&OP[i];
  float4 b = *(const float4*)&OP[i + st];
  ushort4 o;
  o.x = f2bf((a.x + b.x) * inv);
  o.y = f2bf((a.y + b.y) * inv);
  o.z = f2bf((a.z + b.z) * inv);
  o.w = f2bf((a.w + b.w) * inv);
  *(ushort4*)&AO[i] = o;
}

// ---------------- merged output projections: out = AO @ W^T + b (fp32 out) ----------------
__global__ __launch_bounds__(256, 2) void k_gemm_out2(const u16* __restrict__ AO,
                                                      const u16* __restrict__ WOI, const u16* __restrict__ WOC,
                                                      const float* __restrict__ boi, const float* __restrict__ boc,
                                                      float* __restrict__ out) {
  __shared__ u16 smem[32768];
  f32x4 acc[4][4] = {};
  long row0 = (long)blockIdx.x * 128;      // global row in [0,9216)
  long col0 = (long)blockIdx.y * 128;
  int b = (int)(row0 / 4608);
  int s0 = (int)(row0 % 4608);
  const bool ctx = s0 < 512;               // 512 % 128 == 0 -> uniform per block
  const u16* W = ctx ? WOC : WOI;
  const float* bias = ctx ? boc : boi;
  float* ob = ctx ? out + 8388608 + ((long)b * 512 + s0) * 1024
                  : out + ((long)b * 4096 + (s0 - 512)) * 1024;
  gemm_bk64(AO, W, 1024, 1024, row0, col0, 0, 1024, smem, acc);
  EPI_VARS
#pragma unroll
  for (int mf = 0; mf < 4; ++mf)
#pragma unroll
    for (int nf = 0; nf < 4; ++nf)
#pragma unroll
      for (int r = 0; r < 4; ++r) {
        long m = wm * 64 + mf * 16 + mrow + r;        // local row within tile
        long n = col0 + wn * 64 + nf * 16 + ncol;
        ob[m * 1024 + n] = acc[mf][nf][r] + bias[n];
      }
}

// ---------------- launch ----------------
extern "C" void kernel_launch(void* const* d_in, const int* in_sizes, int n_in,
                              void* d_out, int out_size, void* d_ws, size_t ws_size,
                              hipStream_t stream) {
  const float* input   = (const float*)d_in[0];
  const float* context = (const float*)d_in[1];
  const float* Wqi     = (const float*)d_in[2];
  const float* bqi     = (const float*)d_in[3];
  const float* Wqc     = (const float*)d_in[4];
  const float* bqc     = (const float*)d_in[5];
  const float* qsi     = (const float*)d_in[6];
  const float* ksi     = (const float*)d_in[7];
  const float* qsc     = (const float*)d_in[8];
  const float* ksc     = (const float*)d_in[9];
  const float* Woi     = (const float*)d_in[10];
  const float* boi     = (const float*)d_in[11];
  const float* Woc     = (const float*)d_in[12];
  const float* boc     = (const float*)d_in[13];
  float* out = (float*)d_out;

  uint8_t* ws = (uint8_t*)d_ws;
  // workspace layout (bytes)
  u16* XIN  = (u16*)(ws + 0);            // 2*4096*1024 bf16       = 16,777,216
  u16* XCTX = (u16*)(ws + 16777216);     // 2*512*1024             =  2,097,152
  u16* WQI  = (u16*)(ws + 18874368);     // 3072*1024              =  6,291,456
  u16* WQC  = (u16*)(ws + 25165824);     // 3072*1024              =  6,291,456
  u16* WOI  = (u16*)(ws + 31457280);     // 1024*1024              =  2,097,152
  u16* WOC  = (u16*)(ws + 33554432);     // 1024*1024              =  2,097,152
  u16* QB   = (u16*)(ws + 35651584);     // 2*4608*1024            = 18,874,368
  u16* KB   = (u16*)(ws + 54525952);     // 2*4608*1024            = 18,874,368
  u16* VT   = (u16*)(ws + 73400320);     // 2*1024*4608            = 18,874,368
  u16* AO   = (u16*)(ws + 92274688);     // 2*4608*1024            = 18,874,368
  float* S32 = (float*)(ws + 111149056); // region: 2x fp32 O-partials (75,497,472)
  float* RS  = (float*)(ws + 186646528); // 4608 fp32 row sums            = 18,432
  float* RSP = (float*)(ws + 186664960); // 4608 x 36 fp32 row partials   = 663,552
  u16* PB   = (u16*)(ws + 196083712);    // 4608*4608 bf16 (per-batch, reused) = 42,467,328
  // total = 238,551,040 bytes

  // fp32 -> bf16 conversions (single launch)
  k_conv_all<<<dim3(17408), 256, 0, stream>>>(input, XIN, context, XCTX, Wqi, WQI,
                                              Wqc, WQC, Woi, WOI, Woc, WOC);

  // QKV projections, input (bx 0..63) + context (bx 64..71) in one launch
  k_gemm_qkv<<<dim3(72, 24), 256, 0, stream>>>(XIN, XCTX, WQI, WQC, bqi, bqc, QB, KB, VT);

  // RMSNorm + RoPE in place on q,k
  k_normrope<<<dim3(9216, 2), 256, 0, stream>>>(QB, KB, qsi, ksi, qsc, ksc);

  // attention, one batch at a time (P buffer reused; O-partials alias S32)
  for (int b = 0; b < 2; ++b) {
    const u16* Qb  = QB + (long)b * 4608 * 1024;
    const u16* Kbp = KB + (long)b * 4608 * 1024;
    const u16* VTb = VT + (long)b * 1024 * 4608;
    u16* AOb = AO + (long)b * 4608 * 1024;
    k_gemm_p<<<dim3(36, 36), 256, 0, stream>>>(Qb, Kbp, PB, RSP);
    k_rsfin<<<dim3(18), 256, 0, stream>>>(RSP, RS);
    k_gemm_o<<<dim3(36, 8, 2), 256, 0, stream>>>(PB, VTb, (float*)S32);
    k_reduce2div<<<dim3(4608), 256, 0, stream>>>((const float*)S32, RS, AOb);
  }

  // merged output projections
  k_gemm_out2<<<dim3(72, 8), 256, 0, stream>>>(AO, WOI, WOC, boi, boc, out);
}